// Round 1
// baseline (243.304 us; speedup 1.0000x reference)
//
#include <hip/hip_runtime.h>
#include <hip/hip_bf16.h>

typedef __attribute__((ext_vector_type(8))) short bf16x8;
typedef __attribute__((ext_vector_type(4))) float f32x4;

#define LDS_BYTES 151552   // 32768 (xw/attn_out) + 8 waves * 14848 (q:5120 k:5120 vT:4608; P reuses q+k)

__device__ __forceinline__ short f2bf(float f) {
    union { float f; unsigned u; } v; v.f = f;
    unsigned r = v.u + 0x7FFFu + ((v.u >> 16) & 1u);
    return (short)(r >> 16);
}

// One-time: transpose+convert weights to bf16.  wqkvT[768][256], wprojT[256][256]
__global__ void prep_weights(const float* __restrict__ wqkv,
                             const float* __restrict__ wproj,
                             short* __restrict__ wqkvT,
                             short* __restrict__ wprojT) {
    const int n = blockIdx.x, k = threadIdx.x;   // 1024 blocks x 256 threads
    if (n < 768) wqkvT[n * 256 + k] = f2bf(wqkv[k * 768 + n]);
    else         wprojT[(n - 768) * 256 + k] = f2bf(wproj[k * 256 + (n - 768)]);
}

// Fused shifted-window attention: 1 block = 1 window (49 tokens), 8 waves = 8 heads.
__launch_bounds__(512, 2)
__global__ void winattn_fused(const float* __restrict__ x,
                              const float* __restrict__ bqkv,
                              const float* __restrict__ bproj,
                              const short* __restrict__ wqkvT,
                              const short* __restrict__ wprojT,
                              float* __restrict__ out) {
    extern __shared__ char smem[];
    const int tid = threadIdx.x;
    const int wid = blockIdx.x;
    const int b  = wid >> 6;
    const int wh = (wid >> 3) & 7;
    const int ww = wid & 7;

    // ---------- Phase 1: stage rolled window -> LDS bf16 [64][256], XOR-swizzled ----------
    {
        const int r  = tid >> 3;            // 0..63
        const int cb = (tid & 7) << 5;      // 32 cols per thread
        if (r < 49) {
            const int i = r / 7, j = r - i * 7;
            int h  = wh * 7 + i + 3; if (h  >= 56) h  -= 56;   // undo roll(-3)
            int wc = ww * 7 + j + 3; if (wc >= 56) wc -= 56;
            const float* src = x + (((size_t)(b * 56 + h)) * 56 + wc) * 256 + cb;
            #pragma unroll
            for (int c = 0; c < 4; ++c) {
                f32x4 f0 = *(const f32x4*)(src + c * 8);
                f32x4 f1 = *(const f32x4*)(src + c * 8 + 4);
                bf16x8 o;
                #pragma unroll
                for (int q = 0; q < 4; ++q) { o[q] = f2bf(f0[q]); o[q + 4] = f2bf(f1[q]); }
                const int colbyte = (cb + c * 8) * 2;
                *(bf16x8*)(smem + r * 512 + (colbyte ^ ((r & 7) << 4))) = o;
            }
        } else {                             // zero pad rows 49..63 (keeps downstream finite)
            bf16x8 z;
            #pragma unroll
            for (int q = 0; q < 8; ++q) z[q] = 0;
            #pragma unroll
            for (int c = 0; c < 4; ++c) {
                const int colbyte = (cb + c * 8) * 2;
                *(bf16x8*)(smem + r * 512 + (colbyte ^ ((r & 7) << 4))) = z;
            }
        }
    }
    __syncthreads();

    const int wv  = tid >> 6;     // wave = head (0..7)
    const int l   = tid & 63;
    const int l15 = l & 15;
    const int l4  = l >> 4;

    char*  wbase = smem + 32768 + wv * 14848;
    short* qb  = (short*)wbase;               // [64][40] bf16
    short* kb  = (short*)(wbase + 5120);      // [64][40] bf16
    short* vtb = (short*)(wbase + 10240);     // [32][72] bf16 (v transposed: [c][token])
    short* pb  = (short*)wbase;               // [64][72] bf16 (P, reuses q+k space)

    // ---------- Phase 2: q,k,v = xw @ w_qkv + b  (per-head 32 cols each) ----------
    f32x4 acc[3][2][4];
    #pragma unroll
    for (int s = 0; s < 3; ++s)
        #pragma unroll
        for (int c = 0; c < 2; ++c)
            #pragma unroll
            for (int r = 0; r < 4; ++r) acc[s][c][r] = (f32x4){0.f, 0.f, 0.f, 0.f};

    #pragma unroll
    for (int kk = 0; kk < 8; ++kk) {
        bf16x8 a[4];
        #pragma unroll
        for (int rt = 0; rt < 4; ++rt) {
            const int row = rt * 16 + l15;
            a[rt] = *(const bf16x8*)(smem + row * 512 + (((kk << 6) + (l4 << 4)) ^ ((row & 7) << 4)));
        }
        #pragma unroll
        for (int sel = 0; sel < 3; ++sel) {
            #pragma unroll
            for (int ct = 0; ct < 2; ++ct) {
                const short* bp = wqkvT + (((sel << 8) + (wv << 5) + (ct << 4) + l15) << 8)
                                        + (kk << 5) + (l4 << 3);
                bf16x8 bfr = *(const bf16x8*)bp;
                #pragma unroll
                for (int rt = 0; rt < 4; ++rt)
                    acc[sel][ct][rt] = __builtin_amdgcn_mfma_f32_16x16x32_bf16(a[rt], bfr, acc[sel][ct][rt], 0, 0, 0);
            }
        }
    }

    // bias (+ scale on q), convert, stash to per-wave LDS
    #pragma unroll
    for (int sel = 0; sel < 3; ++sel) {
        #pragma unroll
        for (int ct = 0; ct < 2; ++ct) {
            const float bias = bqkv[(sel << 8) + (wv << 5) + (ct << 4) + l15];
            #pragma unroll
            for (int rt = 0; rt < 4; ++rt) {
                #pragma unroll
                for (int rg = 0; rg < 4; ++rg) {
                    const int row = rt * 16 + l4 * 4 + rg;
                    const float v = acc[sel][ct][rt][rg] + bias;
                    if (sel == 0)      qb[row * 40 + (ct << 4) + l15] = f2bf(v * 0.17677669529663687f);
                    else if (sel == 1) kb[row * 40 + (ct << 4) + l15] = f2bf(v);
                    else               vtb[((ct << 4) + l15) * 72 + row] = f2bf(v);
                }
            }
        }
    }
    __syncthreads();

    // ---------- Phase 3: S = q k^T ; masked softmax ; O = P v ----------
    f32x4 sS[4][4];
    #pragma unroll
    for (int r = 0; r < 4; ++r)
        #pragma unroll
        for (int c = 0; c < 4; ++c) sS[r][c] = (f32x4){0.f, 0.f, 0.f, 0.f};

    bf16x8 qa[4];
    #pragma unroll
    for (int rt = 0; rt < 4; ++rt)
        qa[rt] = *(const bf16x8*)(qb + (rt * 16 + l15) * 40 + (l4 << 3));
    #pragma unroll
    for (int ct = 0; ct < 4; ++ct) {
        bf16x8 kf = *(const bf16x8*)(kb + (ct * 16 + l15) * 40 + (l4 << 3));
        #pragma unroll
        for (int rt = 0; rt < 4; ++rt)
            sS[rt][ct] = __builtin_amdgcn_mfma_f32_16x16x32_bf16(qa[rt], kf, sS[rt][ct], 0, 0, 0);
    }

    const bool c3ok = (l15 == 0);             // col = 48 is the only valid ct=3 column
    #pragma unroll
    for (int rt = 0; rt < 4; ++rt) {
        #pragma unroll
        for (int rg = 0; rg < 4; ++rg) {
            float a0 = sS[rt][0][rg], a1 = sS[rt][1][rg], a2 = sS[rt][2][rg];
            float a3 = c3ok ? sS[rt][3][rg] : -1e30f;
            float m = fmaxf(fmaxf(a0, a1), fmaxf(a2, a3));
            #pragma unroll
            for (int d = 1; d < 16; d <<= 1) m = fmaxf(m, __shfl_xor(m, d, 64));
            float e0 = __expf(a0 - m), e1 = __expf(a1 - m), e2 = __expf(a2 - m);
            float e3 = c3ok ? __expf(a3 - m) : 0.f;
            float sum = e0 + e1 + e2 + e3;
            #pragma unroll
            for (int d = 1; d < 16; d <<= 1) sum += __shfl_xor(sum, d, 64);
            const float inv = 1.f / sum;
            const int row = rt * 16 + l4 * 4 + rg;
            pb[row * 72 +      l15] = f2bf(e0 * inv);
            pb[row * 72 + 16 + l15] = f2bf(e1 * inv);
            pb[row * 72 + 32 + l15] = f2bf(e2 * inv);
            pb[row * 72 + 48 + l15] = f2bf(e3 * inv);   // 0 for masked cols -> PV unaffected
        }
    }
    __syncthreads();

    f32x4 o[4][2];
    #pragma unroll
    for (int r = 0; r < 4; ++r)
        #pragma unroll
        for (int c = 0; c < 2; ++c) o[r][c] = (f32x4){0.f, 0.f, 0.f, 0.f};

    #pragma unroll
    for (int kk = 0; kk < 2; ++kk) {
        bf16x8 pa[4];
        #pragma unroll
        for (int rt = 0; rt < 4; ++rt)
            pa[rt] = *(const bf16x8*)(pb + (rt * 16 + l15) * 72 + (kk << 5) + (l4 << 3));
        #pragma unroll
        for (int ct = 0; ct < 2; ++ct) {
            bf16x8 vf = *(const bf16x8*)(vtb + ((ct << 4) + l15) * 72 + (kk << 5) + (l4 << 3));
            #pragma unroll
            for (int rt = 0; rt < 4; ++rt)
                o[rt][ct] = __builtin_amdgcn_mfma_f32_16x16x32_bf16(pa[rt], vf, o[rt][ct], 0, 0, 0);
        }
    }

    // heads concat -> reuse xw LDS (swizzled) as proj input
    #pragma unroll
    for (int ct = 0; ct < 2; ++ct) {
        #pragma unroll
        for (int rt = 0; rt < 4; ++rt) {
            #pragma unroll
            for (int rg = 0; rg < 4; ++rg) {
                const int row = rt * 16 + l4 * 4 + rg;
                const int col = (wv << 5) + (ct << 4) + l15;
                *(short*)(smem + row * 512 + ((col * 2) ^ ((row & 7) << 4))) = f2bf(o[rt][ct][rg]);
            }
        }
    }
    __syncthreads();

    // ---------- Phase 4: proj GEMM + bias + scatter to un-rolled positions ----------
    f32x4 po[2][4];
    #pragma unroll
    for (int c = 0; c < 2; ++c)
        #pragma unroll
        for (int r = 0; r < 4; ++r) po[c][r] = (f32x4){0.f, 0.f, 0.f, 0.f};

    #pragma unroll
    for (int kk = 0; kk < 8; ++kk) {
        bf16x8 a[4];
        #pragma unroll
        for (int rt = 0; rt < 4; ++rt) {
            const int row = rt * 16 + l15;
            a[rt] = *(const bf16x8*)(smem + row * 512 + (((kk << 6) + (l4 << 4)) ^ ((row & 7) << 4)));
        }
        #pragma unroll
        for (int ct = 0; ct < 2; ++ct) {
            const short* bp = wprojT + (((wv << 5) + (ct << 4) + l15) << 8) + (kk << 5) + (l4 << 3);
            bf16x8 bfr = *(const bf16x8*)bp;
            #pragma unroll
            for (int rt = 0; rt < 4; ++rt)
                po[ct][rt] = __builtin_amdgcn_mfma_f32_16x16x32_bf16(a[rt], bfr, po[ct][rt], 0, 0, 0);
        }
    }

    #pragma unroll
    for (int ct = 0; ct < 2; ++ct) {
        const int col = (wv << 5) + (ct << 4) + l15;
        const float bias = bproj[col];
        #pragma unroll
        for (int rt = 0; rt < 4; ++rt) {
            #pragma unroll
            for (int rg = 0; rg < 4; ++rg) {
                const int row = rt * 16 + l4 * 4 + rg;
                if (row < 49) {
                    const int i = row / 7, j = row - i * 7;
                    int h  = wh * 7 + i + 3; if (h  >= 56) h  -= 56;
                    int wc = ww * 7 + j + 3; if (wc >= 56) wc -= 56;
                    out[(((size_t)(b * 56 + h)) * 56 + wc) * 256 + col] = po[ct][rt][rg] + bias;
                }
            }
        }
    }
}

extern "C" void kernel_launch(void* const* d_in, const int* in_sizes, int n_in,
                              void* d_out, int out_size, void* d_ws, size_t ws_size,
                              hipStream_t stream) {
    const float* x     = (const float*)d_in[0];
    const float* wqkv  = (const float*)d_in[1];
    const float* bqkv  = (const float*)d_in[2];
    const float* wproj = (const float*)d_in[3];
    const float* bproj = (const float*)d_in[4];
    float* out = (float*)d_out;

    short* wqkvT  = (short*)d_ws;              // 768*256*2 = 393216 B
    short* wprojT = wqkvT + 768 * 256;         // 256*256*2 = 131072 B

    prep_weights<<<dim3(1024), dim3(256), 0, stream>>>(wqkv, wproj, wqkvT, wprojT);

    (void)hipFuncSetAttribute((const void*)winattn_fused,
                              hipFuncAttributeMaxDynamicSharedMemorySize, LDS_BYTES);
    winattn_fused<<<dim3(2048), dim3(512), LDS_BYTES, stream>>>(x, bqkv, bproj, wqkvT, wprojT, out);
}